// Round 18
// baseline (61.025 us; speedup 1.0000x reference)
//
#include <hip/hip_runtime.h>

// VectorQuantizer on MI355X (gfx950) — single-pass fp16 MFMA scan + exact rescore.
// Round 17: TLP was pinned by the 70KB codebook LDS (2 blocks/CU, big blocks
// don't co-schedule). Stage the codebook in TWO 32KB halves (scan h0, barrier,
// restage, barrier, scan h1; keys persist in regs) -> ~37KB LDS -> 4x512-thr
// blocks/CU = 8 waves/SIMD potential. Also: per-r2-slot top-3 key chains (4x
// ILP, breaks the 128-step loop-carried insert chain) + exact 24-op merge to
// the lane top-3 == round 16's candidate set exactly -> bit-identical outputs.

#define C_DIM   64
#define N_EMB   512
#define HW      4096
#define N_PIX   (32 * HW)            // 131072
#define ZQ_OFF  1
#define IDX_OFF (1 + N_PIX * C_DIM)
#define NBLK    1024                 // 128 px per block
#define TPB     512                  // 8 waves x 16 px

typedef _Float16 half8 __attribute__((ext_vector_type(8)));
typedef float    f32x4 __attribute__((ext_vector_type(4)));
union FragH { unsigned u[4]; half8 h8; uint4 u4; _Float16 h[8]; };

__device__ __forceinline__ unsigned umn(unsigned a, unsigned b){ return a<b?a:b; }
__device__ __forceinline__ unsigned umx(unsigned a, unsigned b){ return a>b?a:b; }
__device__ __forceinline__ unsigned med3u(unsigned a, unsigned b, unsigned c){
    unsigned r;
    asm("v_med3_u32 %0, %1, %2, %3" : "=v"(r) : "v"(a), "v"(b), "v"(c));
    return r;
}

__global__ __launch_bounds__(TPB, 4) void vq_main(
    const float* __restrict__ z,
    const float* __restrict__ cb,
    float* __restrict__ out,
    float* __restrict__ ws)
{
    __shared__ unsigned cbh[256 * 32];     // 32KB: HALF codebook, fp16 pairs, swizzled
    __shared__ float    esh5[N_EMB];       // esum + 0.5 (scan keys, positive d)
    __shared__ float    eshx[N_EMB];       // numpy-exact esum (rescore)
    __shared__ float    wsum[8];

    const int t = threadIdx.x;             // 0..511

    // ---- Prologue: numpy-exact esum for all 512 codes (thread t = code t) ----
    {
        const float* e = cb + t * C_DIM;
        float ev[64];
        #pragma unroll
        for (int q = 0; q < 16; ++q) {
            float4 v = ((const float4*)e)[q];
            ev[4*q+0]=v.x; ev[4*q+1]=v.y; ev[4*q+2]=v.z; ev[4*q+3]=v.w;
        }
        float r[8];
        #pragma unroll
        for (int i = 0; i < 8; ++i) r[i] = __fmul_rn(ev[i], ev[i]);
        #pragma unroll
        for (int k = 8; k < 64; k += 8) {
            #pragma unroll
            for (int i = 0; i < 8; ++i)
                r[i] = __fadd_rn(r[i], __fmul_rn(ev[k+i], ev[k+i]));
        }
        float es = __fadd_rn(
            __fadd_rn(__fadd_rn(r[0],r[1]), __fadd_rn(r[2],r[3])),
            __fadd_rn(__fadd_rn(r[4],r[5]), __fadd_rn(r[6],r[7])));
        eshx[t] = es;
        esh5[t] = es + 0.5f;
    }

    const int l   = t & 63;
    const int wv  = t >> 6;                // wave 0..7
    const int lg  = l >> 4;                // k-chunk group 0..3
    const int li  = l & 15;                // pixel col / code row in tile
    const int bb  = blockIdx.x >> 5;       // batch (128 px/block, 4096 px/image)
    const int g20 = (lg)     ^ (li & 7);   // swizzled granule, k-step 0
    const int g21 = (4 + lg) ^ (li & 7);   // swizzled granule, k-step 1
    const int jb  = lg * 4;
    float ls = 0.f;

    // ---- staging helper: 2 threads per code (ch = granule half) ----
    const int jh = t >> 1, ch = t & 1, rs = jh & 7;
    auto stage = [&](int h) {
        const float* e = cb + ((h << 8) + jh) * C_DIM + ch * 32;
        unsigned pw[16];
        #pragma unroll
        for (int w2 = 0; w2 < 16; ++w2) {
            union { _Float16 hh[2]; unsigned u; } pk;
            pk.hh[0] = (_Float16)(e[2*w2]   * 512.0f);
            pk.hh[1] = (_Float16)(e[2*w2+1] * 512.0f);
            pw[w2] = pk.u;
        }
        #pragma unroll
        for (int g4 = 0; g4 < 4; ++g4) {
            int g = ch*4 + g4, g2 = g ^ rs;
            *(uint4*)&cbh[jh*32 + g2*4] =
                make_uint4(pw[4*g4], pw[4*g4+1], pw[4*g4+2], pw[4*g4+3]);
        }
    };

    // ---- This wave's 16-px tile; lane's pixel = base + li ----
    const int pxw = blockIdx.x * 128 + wv * 16 + li;
    const float* zb = z + (size_t)bb * (C_DIM * HW) + (pxw & (HW - 1));

    // B-fragments: z as fp16 (overlaps with staging)
    FragH b0, b1;
    {
        const float* c0 = zb + (size_t)(lg*8) * HW;
        const float* c1 = zb + (size_t)(32 + lg*8) * HW;
        #pragma unroll
        for (int i = 0; i < 8; ++i) {
            b0.h[i] = (_Float16)c0[(size_t)i*HW];
            b1.h[i] = (_Float16)c1[(size_t)i*HW];
        }
    }

    stage(0);
    __syncthreads();

    // ---- scan: per-r2-slot top-3 keys (4 independent chains) ----
    unsigned s1[4], s2[4], s3[4];
    #pragma unroll
    for (int i = 0; i < 4; ++i) { s1[i]=0xFFFFFFFFu; s2[i]=0xFFFFFFFFu; s3[i]=0xFFFFFFFFu; }

    auto scan = [&](int h) {
        #pragma unroll 4
        for (int T = 0; T < 16; ++T) {
            const int row = T*16 + li;
            FragH a0, a1;
            a0.u4 = *(const uint4*)&cbh[row*32 + g20*4];
            a1.u4 = *(const uint4*)&cbh[row*32 + g21*4];
            f32x4 es = *(const f32x4*)&esh5[(h<<8) + T*16 + jb];
            f32x4 acc = {0.f,0.f,0.f,0.f};
            acc = __builtin_amdgcn_mfma_f32_16x16x32_f16(a0.h8, b0.h8, acc, 0,0,0);
            acc = __builtin_amdgcn_mfma_f32_16x16x32_f16(a1.h8, b1.h8, acc, 0,0,0);
            const int jT = (h<<8) + T*16 + jb;
            #pragma unroll
            for (int r2 = 0; r2 < 4; ++r2) {
                float d = __fmaf_rn(-0.00390625f, acc[r2], es[r2]);  // >0 -> sortable
                unsigned key = (__float_as_uint(d) & 0xFFFFFE00u) | (unsigned)(jT + r2);
                unsigned nk3 = med3u(key, s2[r2], s3[r2]);   // independent chain per r2
                unsigned nk2 = med3u(key, s1[r2], s2[r2]);
                s1[r2] = umn(s1[r2], key); s2[r2] = nk2; s3[r2] = nk3;
            }
        }
    };

    scan(0);
    __syncthreads();
    stage(1);
    __syncthreads();
    scan(1);

    // ---- merge 4 sorted triples -> lane-global top-3 (exact; == round 16 set) ----
    unsigned k1, k2, k3;
    {
        // merge3(a,b): top-3 of two sorted triples
        #define MERGE3(o1,o2,o3, a1,a2,a3, b1,b2,b3)                         \
            o1 = umn(a1, b1);                                                \
            o2 = med3u(a1, b1, umn(a2, b2));                                 \
            o3 = umn(umn(a3, b3), umn(umx(a2, b1), umx(a1, b2)));
        unsigned m1,m2,m3, n1,n2,n3;
        MERGE3(m1,m2,m3, s1[0],s2[0],s3[0], s1[1],s2[1],s3[1]);
        MERGE3(n1,n2,n3, s1[2],s2[2],s3[2], s1[3],s2[3],s3[3]);
        MERGE3(k1,k2,k3, m1,m2,m3, n1,n2,n3);
        #undef MERGE3
    }

    // ---- rescore: every lane handles its own 3 candidates ----
    float zr[64];
    #pragma unroll
    for (int c = 0; c < 64; ++c) zr[c] = zb[(size_t)c * HW];
    float ap;
    {   // numpy-exact ||z||^2
        float r[8];
        #pragma unroll
        for (int i = 0; i < 8; ++i) r[i] = __fmul_rn(zr[i], zr[i]);
        #pragma unroll
        for (int k = 8; k < 64; k += 8) {
            #pragma unroll
            for (int i = 0; i < 8; ++i)
                r[i] = __fadd_rn(r[i], __fmul_rn(zr[k+i], zr[k+i]));
        }
        ap = __fadd_rn(
            __fadd_rn(__fadd_rn(r[0],r[1]), __fadd_rn(r[2],r[3])),
            __fadd_rn(__fadd_rn(r[4],r[5]), __fadd_rn(r[6],r[7])));
    }

    // pixel-global kmin over 12 candidates (butterfly within same-li group)
    unsigned kmin = k1;
    kmin = umn(kmin, __shfl_xor(kmin, 16, 64));
    kmin = umn(kmin, __shfl_xor(kmin, 32, 64));
    const float thr = __uint_as_float(kmin & 0xFFFFFE00u) + 1.2e-4f;
    float bd = 3.0e38f; int bj = 1023;

    #define RESCORE(K) do {                                               \
        float da_ = __uint_as_float((K) & 0xFFFFFE00u);                   \
        if (da_ <= thr) {                                                 \
            int j_ = (int)((K) & 511u);                                   \
            const float* er_ = cb + (size_t)j_ * 64;                      \
            float a_ = 0.f;                                               \
            _Pragma("unroll")                                             \
            for (int c_ = 0; c_ < 64; ++c_)                               \
                a_ = __fmaf_rn(zr[c_], er_[c_], a_);                      \
            float dd_ = __fsub_rn(__fadd_rn(ap, eshx[j_]),                \
                                  __fmul_rn(2.0f, a_));                   \
            if (dd_ < bd || (dd_ == bd && j_ < bj)) { bd = dd_; bj = j_; }\
        }                                                                 \
    } while (0)
    RESCORE(k1); RESCORE(k2); RESCORE(k3);
    #undef RESCORE

    // lexicographic (d, j) butterfly merge across the 4 lg groups
    #pragma unroll
    for (int m = 16; m <= 32; m <<= 1) {
        float od = __shfl_xor(bd, m, 64);
        int   oj = __shfl_xor(bj, m, 64);
        if (od < bd || (od == bd && oj < bj)) { bd = od; bj = oj; }
    }
    if (l < 16) {                          // one lane-group writes idx + loss
        out[IDX_OFF + pxw] = (float)bj;
        ls += bd;                          // exact ||z - e_bj||^2 (incl. ap)
    }

    // ---- z_q write: lane (cq,li) writes c-planes [cq*16, cq*16+16) ----
    {
        const int cq = l >> 4;
        const float* eb = cb + (size_t)bj * 64;
        float* zq = out + ZQ_OFF + (size_t)bb * (C_DIM * HW) + (pxw & (HW - 1));
        #pragma unroll
        for (int cc = 0; cc < 16; ++cc) {
            int c = cq * 16 + cc;
            zq[(size_t)c * HW] = eb[c];    // 16 px x 4 planes per instr
        }
    }

    // ---- loss reduce: wave -> block -> ws ----
    #pragma unroll
    for (int off = 32; off; off >>= 1) ls += __shfl_down(ls, off, 64);
    if (l == 0) wsum[wv] = ls;
    __syncthreads();
    if (t == 0) {
        float s = 0.f;
        #pragma unroll
        for (int i = 0; i < 8; ++i) s += wsum[i];
        ws[blockIdx.x] = s;
    }
}

__global__ __launch_bounds__(256) void vq_loss(
    const float* __restrict__ ws, float* __restrict__ out)
{
    __shared__ float sm[4];
    float v = (ws[threadIdx.x]       + ws[threadIdx.x + 256])
            + (ws[threadIdx.x + 512] + ws[threadIdx.x + 768]);   // 1024 partials
    #pragma unroll
    for (int off = 32; off; off >>= 1) v += __shfl_down(v, off, 64);
    const int lane = threadIdx.x & 63, wid = threadIdx.x >> 6;
    if (lane == 0) sm[wid] = v;
    __syncthreads();
    if (threadIdx.x == 0)
        out[0] = ((sm[0] + sm[1]) + (sm[2] + sm[3])) * (1.0f / 8388608.0f);
}

extern "C" void kernel_launch(void* const* d_in, const int* in_sizes, int n_in,
                              void* d_out, int out_size, void* d_ws, size_t ws_size,
                              hipStream_t stream)
{
    const float* z  = (const float*)d_in[0];   // 8388608 f32
    const float* cb = (const float*)d_in[1];   // 32768 f32
    float* out = (float*)d_out;
    float* ws  = (float*)d_ws;                 // 1024 f32 partials

    vq_main<<<NBLK, TPB, 0, stream>>>(z, cb, out, ws);
    vq_loss<<<1, 256, 0, stream>>>(ws, out);
}

// Round 19
// 42.117 us; speedup vs baseline: 1.4489x; 1.4489x over previous
//
#include <hip/hip_runtime.h>

// VectorQuantizer on MI355X (gfx950) — fp16 MFMA scan + exact rescore, r18.
// (1) acc-init: stage fp16(-512e), init MFMA C with 256*(es+0.5) -> acc ends
//     as 256*d, positive & uint-sortable: kills 128 fmaf + esum loads in scan.
// (2) per-r2 top-3 chains (4x ILP) + exact triple-merge (superset candidates).
// (3) wave-uniform rescore skip: if all 16 px have approx top-2 gap > the
//     proven 1.2e-4 window, skip zr reload/exact-ap/rescore entirely; loss
//     from centered key decode + free fp32 ||z||^2 (B-build butterfly).
//     Ambiguous waves (~25%) run the unchanged numpy-bit-exact rescore.

#define C_DIM   64
#define N_EMB   512
#define HW      4096
#define N_PIX   (32 * HW)            // 131072
#define ZQ_OFF  1
#define IDX_OFF (1 + N_PIX * C_DIM)
#define NBLK    512                  // 256 px per block
#define TPB     1024                 // 16 waves x 16 px

typedef _Float16 half8 __attribute__((ext_vector_type(8)));
typedef float    f32x4 __attribute__((ext_vector_type(4)));
union FragH { unsigned u[4]; half8 h8; uint4 u4; _Float16 h[8]; };

__device__ __forceinline__ unsigned umn(unsigned a, unsigned b){ return a<b?a:b; }
__device__ __forceinline__ unsigned umx(unsigned a, unsigned b){ return a>b?a:b; }
__device__ __forceinline__ unsigned med3u(unsigned a, unsigned b, unsigned c){
    unsigned r;
    asm("v_med3_u32 %0, %1, %2, %3" : "=v"(r) : "v"(a), "v"(b), "v"(c));
    return r;
}

__global__ __launch_bounds__(TPB, 4) void vq_main(
    const float* __restrict__ z,
    const float* __restrict__ cb,
    float* __restrict__ out,
    float* __restrict__ ws)
{
    __shared__ unsigned cbh[N_EMB * 32];   // 64KB codebook fp16(-512e) pairs, swizzled
    __shared__ float    esh5[N_EMB];       // 256*(es+0.5)  (MFMA C-init)
    __shared__ float    eshx[N_EMB];       // numpy-exact esum (rescore)
    __shared__ float    wsum[16];

    const int t = threadIdx.x;             // 0..1023

    // ---- Stage codebook (threads 0..511: thread t owns code row t) ----
    if (t < N_EMB) {
        const float* e = cb + t * C_DIM;
        float ev[64];
        #pragma unroll
        for (int q = 0; q < 16; ++q) {
            float4 v = ((const float4*)e)[q];
            ev[4*q+0]=v.x; ev[4*q+1]=v.y; ev[4*q+2]=v.z; ev[4*q+3]=v.w;
        }
        // numpy pairwise_sum(n=64): 8 accs, rounded mul, tree combine
        float r[8];
        #pragma unroll
        for (int i = 0; i < 8; ++i) r[i] = __fmul_rn(ev[i], ev[i]);
        #pragma unroll
        for (int k = 8; k < 64; k += 8) {
            #pragma unroll
            for (int i = 0; i < 8; ++i)
                r[i] = __fadd_rn(r[i], __fmul_rn(ev[k+i], ev[k+i]));
        }
        float es = __fadd_rn(
            __fadd_rn(__fadd_rn(r[0],r[1]), __fadd_rn(r[2],r[3])),
            __fadd_rn(__fadd_rn(r[4],r[5]), __fadd_rn(r[6],r[7])));
        eshx[t] = es;
        esh5[t] = __fmul_rn(__fadd_rn(es, 0.5f), 256.0f);   // x256 exact (pow2)
        unsigned hw_[32];
        #pragma unroll
        for (int w2 = 0; w2 < 32; ++w2) {
            union { _Float16 hh[2]; unsigned u; } pk;
            pk.hh[0] = (_Float16)(ev[2*w2]   * -512.0f);    // negated!
            pk.hh[1] = (_Float16)(ev[2*w2+1] * -512.0f);
            hw_[w2] = pk.u;
        }
        const int rs = t & 7;
        #pragma unroll
        for (int g = 0; g < 8; ++g) {
            int g2 = g ^ rs;
            *(uint4*)&cbh[t*32 + g2*4] =
                make_uint4(hw_[4*g], hw_[4*g+1], hw_[4*g+2], hw_[4*g+3]);
        }
    }
    __syncthreads();

    const int l   = t & 63;
    const int wv  = t >> 6;                // wave 0..15
    const int lg  = l >> 4;                // k-chunk / candidate group 0..3
    const int li  = l & 15;                // pixel col / code row in tile
    const int bb  = blockIdx.x >> 4;       // batch (256 px per block, 4096 per b)
    const int g20 = (lg)     ^ (li & 7);   // swizzled granule, k-step 0
    const int g21 = (4 + lg) ^ (li & 7);   // swizzled granule, k-step 1
    const int jb  = lg * 4;
    float ls = 0.f;

    // ---- This wave's single 16-px tile; lane's pixel = base + li ----
    const int pxw = blockIdx.x * 256 + wv * 16 + li;
    const float* zb = z + (size_t)bb * (C_DIM * HW) + (pxw & (HW - 1));

    // B-fragments: z as fp16; free fp32 partial ||z||^2 on the way
    FragH b0, b1;
    float apx = 0.f;
    {
        const float* c0 = zb + (size_t)(lg*8) * HW;
        const float* c1 = zb + (size_t)(32 + lg*8) * HW;
        #pragma unroll
        for (int i = 0; i < 8; ++i) {
            float x0 = c0[(size_t)i*HW], x1 = c1[(size_t)i*HW];
            b0.h[i] = (_Float16)x0;
            b1.h[i] = (_Float16)x1;
            apx = __fmaf_rn(x0, x0, apx);
            apx = __fmaf_rn(x1, x1, apx);
        }
        apx += __shfl_xor(apx, 16, 64);    // pixel-global fp32 ||z||^2 (approx,
        apx += __shfl_xor(apx, 32, 64);    // used only for skip-path loss)
    }

    // ---- MFMA scan: 32 code-tiles; acc init = 256*(es+0.5); 4 top-3 chains ----
    unsigned s1[4], s2[4], s3[4];
    #pragma unroll
    for (int i = 0; i < 4; ++i) { s1[i]=0xFFFFFFFFu; s2[i]=0xFFFFFFFFu; s3[i]=0xFFFFFFFFu; }
    #pragma unroll 4
    for (int T = 0; T < 32; ++T) {
        const int row = T*16 + li;
        FragH a0, a1;
        a0.u4 = *(const uint4*)&cbh[row*32 + g20*4];
        a1.u4 = *(const uint4*)&cbh[row*32 + g21*4];
        f32x4 acc = *(const f32x4*)&esh5[T*16 + jb];   // C-init: 256*(es+0.5)
        acc = __builtin_amdgcn_mfma_f32_16x16x32_f16(a0.h8, b0.h8, acc, 0,0,0);
        acc = __builtin_amdgcn_mfma_f32_16x16x32_f16(a1.h8, b1.h8, acc, 0,0,0);
        const int jT = T*16 + jb;
        #pragma unroll
        for (int r2 = 0; r2 < 4; ++r2) {
            // acc[r2] = 256*d > 0 -> directly uint-sortable
            unsigned key = (__float_as_uint(acc[r2]) & 0xFFFFFE00u) | (unsigned)(jT + r2);
            unsigned nk3 = med3u(key, s2[r2], s3[r2]);   // independent chain per r2
            unsigned nk2 = med3u(key, s1[r2], s2[r2]);
            s1[r2] = umn(s1[r2], key); s2[r2] = nk2; s3[r2] = nk3;
        }
    }

    // ---- pixel-global approx top-2 (for the skip decision) ----
    unsigned m1, m2;
    {
        unsigned p1 = umn(s1[0], s1[1]);
        unsigned p2 = umn(umx(s1[0], s1[1]), umn(s2[0], s2[1]));
        unsigned q1 = umn(s1[2], s1[3]);
        unsigned q2 = umn(umx(s1[2], s1[3]), umn(s2[2], s2[3]));
        m1 = umn(p1, q1);
        m2 = umn(umx(p1, q1), umn(p2, q2));
        #pragma unroll
        for (int m = 16; m <= 32; m <<= 1) {
            unsigned o1 = __shfl_xor(m1, m, 64), o2 = __shfl_xor(m2, m, 64);
            unsigned nm2 = umn(umx(m1, o1), umn(m2, o2));
            m1 = umn(m1, o1); m2 = nm2;
        }
    }
    const float d1m = __uint_as_float(m1 & 0xFFFFFE00u);   // scaled x256
    const float d2m = __uint_as_float(m2 & 0xFFFFFE00u);
    const bool  amb = (d2m - d1m) <= 0.030720f;            // 256 * 1.2e-4

    int bj;
    if (__ballot(amb) == 0ULL) {
        // ---- SKIP path: approx ordering is decisive for every px in wave ----
        bj = (int)(m1 & 511u);
        if (l < 16) {
            out[IDX_OFF + pxw] = (float)bj;
            // centered decode (+0x100 = half step) -> unbiased d; + fp32 ||z||^2
            float dd = __uint_as_float((m1 & 0xFFFFFE00u) | 0x100u);
            ls += __fmaf_rn(dd, 0.00390625f, apx - 0.5f);  // ap + es - 2z.e
        }
    } else {
        // ---- RESCORE path (unchanged numpy-bit-exact machinery) ----
        unsigned k1, k2, k3;
        {
            #define MERGE3(o1,o2,o3, a1,a2,a3, b1,b2,b3)                     \
                o1 = umn(a1, b1);                                            \
                o2 = med3u(a1, b1, umn(a2, b2));                             \
                o3 = umn(umn(a3, b3), umn(umx(a2, b1), umx(a1, b2)));
            unsigned x1,x2,x3, y1,y2,y3;
            MERGE3(x1,x2,x3, s1[0],s2[0],s3[0], s1[1],s2[1],s3[1]);
            MERGE3(y1,y2,y3, s1[2],s2[2],s3[2], s1[3],s2[3],s3[3]);
            MERGE3(k1,k2,k3, x1,x2,x3, y1,y2,y3);
            #undef MERGE3
        }
        float zr[64];
        #pragma unroll
        for (int c = 0; c < 64; ++c) zr[c] = zb[(size_t)c * HW];
        float ap;
        {   // numpy-exact ||z||^2
            float r[8];
            #pragma unroll
            for (int i = 0; i < 8; ++i) r[i] = __fmul_rn(zr[i], zr[i]);
            #pragma unroll
            for (int k = 8; k < 64; k += 8) {
                #pragma unroll
                for (int i = 0; i < 8; ++i)
                    r[i] = __fadd_rn(r[i], __fmul_rn(zr[k+i], zr[k+i]));
            }
            ap = __fadd_rn(
                __fadd_rn(__fadd_rn(r[0],r[1]), __fadd_rn(r[2],r[3])),
                __fadd_rn(__fadd_rn(r[4],r[5]), __fadd_rn(r[6],r[7])));
        }
        const float thr = d1m + 0.030720f;   // scaled window, same 1.2e-4
        float bd = 3.0e38f; bj = 1023;

        #define RESCORE(K) do {                                               \
            float da_ = __uint_as_float((K) & 0xFFFFFE00u);                   \
            if (da_ <= thr) {                                                 \
                int j_ = (int)((K) & 511u);                                   \
                const float* er_ = cb + (size_t)j_ * 64;                      \
                float a_ = 0.f;                                               \
                _Pragma("unroll")                                             \
                for (int c_ = 0; c_ < 64; ++c_)                               \
                    a_ = __fmaf_rn(zr[c_], er_[c_], a_);                      \
                float dd_ = __fsub_rn(__fadd_rn(ap, eshx[j_]),                \
                                      __fmul_rn(2.0f, a_));                   \
                if (dd_ < bd || (dd_ == bd && j_ < bj)) { bd = dd_; bj = j_; }\
            }                                                                 \
        } while (0)
        RESCORE(k1); RESCORE(k2); RESCORE(k3);
        #undef RESCORE

        #pragma unroll
        for (int m = 16; m <= 32; m <<= 1) {   // lexicographic (d,j) merge
            float od = __shfl_xor(bd, m, 64);
            int   oj = __shfl_xor(bj, m, 64);
            if (od < bd || (od == bd && oj < bj)) { bd = od; bj = oj; }
        }
        if (l < 16) {
            out[IDX_OFF + pxw] = (float)bj;
            ls += bd;                          // exact ||z - e_bj||^2
        }
    }

    // ---- z_q write (common): lane (cq,li) writes c-planes [cq*16,cq*16+16) ----
    {
        const int cq = l >> 4;
        const float* eb = cb + (size_t)bj * 64;
        float* zq = out + ZQ_OFF + (size_t)bb * (C_DIM * HW) + (pxw & (HW - 1));
        #pragma unroll
        for (int cc = 0; cc < 16; ++cc) {
            int c = cq * 16 + cc;
            zq[(size_t)c * HW] = eb[c];        // 16 px x 4 planes per instr
        }
    }

    // ---- loss reduce: wave -> block -> ws ----
    #pragma unroll
    for (int off = 32; off; off >>= 1) ls += __shfl_down(ls, off, 64);
    if (l == 0) wsum[wv] = ls;
    __syncthreads();
    if (t == 0) {
        float s = 0.f;
        #pragma unroll
        for (int i = 0; i < 16; ++i) s += wsum[i];
        ws[blockIdx.x] = s;
    }
}

__global__ __launch_bounds__(256) void vq_loss(
    const float* __restrict__ ws, float* __restrict__ out)
{
    __shared__ float sm[4];
    float v = ws[threadIdx.x] + ws[threadIdx.x + 256];   // 512 partials
    #pragma unroll
    for (int off = 32; off; off >>= 1) v += __shfl_down(v, off, 64);
    const int lane = threadIdx.x & 63, wid = threadIdx.x >> 6;
    if (lane == 0) sm[wid] = v;
    __syncthreads();
    if (threadIdx.x == 0)
        out[0] = ((sm[0] + sm[1]) + (sm[2] + sm[3])) * (1.0f / 8388608.0f);
}

extern "C" void kernel_launch(void* const* d_in, const int* in_sizes, int n_in,
                              void* d_out, int out_size, void* d_ws, size_t ws_size,
                              hipStream_t stream)
{
    const float* z  = (const float*)d_in[0];   // 8388608 f32
    const float* cb = (const float*)d_in[1];   // 32768 f32
    float* out = (float*)d_out;
    float* ws  = (float*)d_ws;                 // 512 f32 partials

    vq_main<<<NBLK, TPB, 0, stream>>>(z, cb, out, ws);
    vq_loss<<<1, 256, 0, stream>>>(ws, out);
}

// Round 20
// 40.122 us; speedup vs baseline: 1.5210x; 1.0497x over previous
//
#include <hip/hip_runtime.h>

// VectorQuantizer on MI355X (gfx950) — fp16 MFMA scan + exact rescore, r19.
// r18 machinery (acc-init keys, per-r2 top-3 chains, per-tile wave-skip,
// numpy-bit-exact rescore) on r12's 2-tile-per-wave geometry:
//  - a-frags + esh5 LDS reads SHARED by both pixel-tiles (LDS reads halve)
//  - two independent MFMA acc chains per tile pair (2x ILP in the
//    dependency-limited wave; r18 counters showed waves resident but
//    latency-bound, 33% VALU issue)
//  - z_q written r12-style as full 128B lines (32 px x 2 plane-halves).

#define C_DIM   64
#define N_EMB   512
#define HW      4096
#define N_PIX   (32 * HW)            // 131072
#define ZQ_OFF  1
#define IDX_OFF (1 + N_PIX * C_DIM)
#define NBLK    512                  // 256 px per block
#define TPB     512                  // 8 waves x 32 px

typedef _Float16 half8 __attribute__((ext_vector_type(8)));
typedef float    f32x4 __attribute__((ext_vector_type(4)));
union FragH { unsigned u[4]; half8 h8; uint4 u4; _Float16 h[8]; };

__device__ __forceinline__ unsigned umn(unsigned a, unsigned b){ return a<b?a:b; }
__device__ __forceinline__ unsigned umx(unsigned a, unsigned b){ return a>b?a:b; }
__device__ __forceinline__ unsigned med3u(unsigned a, unsigned b, unsigned c){
    unsigned r;
    asm("v_med3_u32 %0, %1, %2, %3" : "=v"(r) : "v"(a), "v"(b), "v"(c));
    return r;
}

__global__ __launch_bounds__(TPB, 4) void vq_main(
    const float* __restrict__ z,
    const float* __restrict__ cb,
    float* __restrict__ out,
    float* __restrict__ ws)
{
    __shared__ unsigned cbh[N_EMB * 32];   // 64KB codebook fp16(-512e) pairs, swizzled
    __shared__ float    esh5[N_EMB];       // 256*(es+0.5)  (MFMA C-init)
    __shared__ float    eshx[N_EMB];       // numpy-exact esum (rescore)
    __shared__ float    wsum[8];

    const int t = threadIdx.x;             // 0..511: thread t stages code t

    // ---- Stage codebook + numpy-exact esum ----
    {
        const float* e = cb + t * C_DIM;
        float ev[64];
        #pragma unroll
        for (int q = 0; q < 16; ++q) {
            float4 v = ((const float4*)e)[q];
            ev[4*q+0]=v.x; ev[4*q+1]=v.y; ev[4*q+2]=v.z; ev[4*q+3]=v.w;
        }
        float r[8];
        #pragma unroll
        for (int i = 0; i < 8; ++i) r[i] = __fmul_rn(ev[i], ev[i]);
        #pragma unroll
        for (int k = 8; k < 64; k += 8) {
            #pragma unroll
            for (int i = 0; i < 8; ++i)
                r[i] = __fadd_rn(r[i], __fmul_rn(ev[k+i], ev[k+i]));
        }
        float es = __fadd_rn(
            __fadd_rn(__fadd_rn(r[0],r[1]), __fadd_rn(r[2],r[3])),
            __fadd_rn(__fadd_rn(r[4],r[5]), __fadd_rn(r[6],r[7])));
        eshx[t] = es;
        esh5[t] = __fmul_rn(__fadd_rn(es, 0.5f), 256.0f);   // x256 exact (pow2)
        unsigned hw_[32];
        #pragma unroll
        for (int w2 = 0; w2 < 32; ++w2) {
            union { _Float16 hh[2]; unsigned u; } pk;
            pk.hh[0] = (_Float16)(ev[2*w2]   * -512.0f);    // negated
            pk.hh[1] = (_Float16)(ev[2*w2+1] * -512.0f);
            hw_[w2] = pk.u;
        }
        const int rs = t & 7;
        #pragma unroll
        for (int g = 0; g < 8; ++g) {
            int g2 = g ^ rs;
            *(uint4*)&cbh[t*32 + g2*4] =
                make_uint4(hw_[4*g], hw_[4*g+1], hw_[4*g+2], hw_[4*g+3]);
        }
    }
    __syncthreads();

    const int l   = t & 63;
    const int wv  = t >> 6;                // wave 0..7
    const int lg  = l >> 4;                // k-chunk / candidate group 0..3
    const int li  = l & 15;                // pixel col / code row in tile
    const int bb  = blockIdx.x >> 4;       // batch (256 px/block, 4096 px/image)
    const int g20 = (lg)     ^ (li & 7);
    const int g21 = (4 + lg) ^ (li & 7);
    const int jb  = lg * 4;
    float ls = 0.f;

    // ---- Wave covers 32 consecutive px: tile A = +li, tile B = +16+li ----
    const int pxw0 = blockIdx.x * 256 + wv * 32;
    const float* zbA = z + (size_t)bb * (C_DIM * HW) + ((pxw0      + li) & (HW-1));
    const float* zbB = z + (size_t)bb * (C_DIM * HW) + ((pxw0 + 16 + li) & (HW-1));

    FragH bA0, bA1, bB0, bB1;
    float apxA = 0.f, apxB = 0.f;
    {
        const float* c0 = zbA + (size_t)(lg*8) * HW;
        const float* c1 = zbA + (size_t)(32 + lg*8) * HW;
        const float* c2 = zbB + (size_t)(lg*8) * HW;
        const float* c3 = zbB + (size_t)(32 + lg*8) * HW;
        #pragma unroll
        for (int i = 0; i < 8; ++i) {
            float x0 = c0[(size_t)i*HW], x1 = c1[(size_t)i*HW];
            float y0 = c2[(size_t)i*HW], y1 = c3[(size_t)i*HW];
            bA0.h[i] = (_Float16)x0;  bA1.h[i] = (_Float16)x1;
            bB0.h[i] = (_Float16)y0;  bB1.h[i] = (_Float16)y1;
            apxA = __fmaf_rn(x0, x0, apxA); apxA = __fmaf_rn(x1, x1, apxA);
            apxB = __fmaf_rn(y0, y0, apxB); apxB = __fmaf_rn(y1, y1, apxB);
        }
        apxA += __shfl_xor(apxA, 16, 64);  apxA += __shfl_xor(apxA, 32, 64);
        apxB += __shfl_xor(apxB, 16, 64);  apxB += __shfl_xor(apxB, 32, 64);
    }

    // ---- MFMA scan: shared a-frags/esh5; two independent acc chains ----
    unsigned sA1[4], sA2[4], sA3[4], sB1[4], sB2[4], sB3[4];
    #pragma unroll
    for (int i = 0; i < 4; ++i) {
        sA1[i]=sA2[i]=sA3[i]=0xFFFFFFFFu;
        sB1[i]=sB2[i]=sB3[i]=0xFFFFFFFFu;
    }
    #pragma unroll 4
    for (int T = 0; T < 32; ++T) {
        const int row = T*16 + li;
        FragH a0, a1;
        a0.u4 = *(const uint4*)&cbh[row*32 + g20*4];
        a1.u4 = *(const uint4*)&cbh[row*32 + g21*4];
        f32x4 es = *(const f32x4*)&esh5[T*16 + jb];   // shared C-init
        f32x4 accA = es, accB = es;
        accA = __builtin_amdgcn_mfma_f32_16x16x32_f16(a0.h8, bA0.h8, accA, 0,0,0);
        accB = __builtin_amdgcn_mfma_f32_16x16x32_f16(a0.h8, bB0.h8, accB, 0,0,0);
        accA = __builtin_amdgcn_mfma_f32_16x16x32_f16(a1.h8, bA1.h8, accA, 0,0,0);
        accB = __builtin_amdgcn_mfma_f32_16x16x32_f16(a1.h8, bB1.h8, accB, 0,0,0);
        const int jT = T*16 + jb;
        #pragma unroll
        for (int r2 = 0; r2 < 4; ++r2) {
            unsigned keyA = (__float_as_uint(accA[r2]) & 0xFFFFFE00u) | (unsigned)(jT + r2);
            unsigned keyB = (__float_as_uint(accB[r2]) & 0xFFFFFE00u) | (unsigned)(jT + r2);
            unsigned nA3 = med3u(keyA, sA2[r2], sA3[r2]);
            unsigned nA2 = med3u(keyA, sA1[r2], sA2[r2]);
            sA1[r2] = umn(sA1[r2], keyA); sA2[r2] = nA2; sA3[r2] = nA3;
            unsigned nB3 = med3u(keyB, sB2[r2], sB3[r2]);
            unsigned nB2 = med3u(keyB, sB1[r2], sB2[r2]);
            sB1[r2] = umn(sB1[r2], keyB); sB2[r2] = nB2; sB3[r2] = nB3;
        }
    }

    // ---- per-tile: skip decision + (skip | exact rescore) ----
    int bjA, bjB;
    #pragma unroll
    for (int pt = 0; pt < 2; ++pt) {
        unsigned (&s1)[4] = pt ? sB1 : sA1;
        unsigned (&s2)[4] = pt ? sB2 : sA2;
        unsigned (&s3)[4] = pt ? sB3 : sA3;
        const float* zb = pt ? zbB : zbA;
        const float apx = pt ? apxB : apxA;
        const int   px  = pxw0 + pt*16 + li;

        // pixel-global approx top-2
        unsigned m1, m2;
        {
            unsigned p1 = umn(s1[0], s1[1]);
            unsigned p2 = umn(umx(s1[0], s1[1]), umn(s2[0], s2[1]));
            unsigned q1 = umn(s1[2], s1[3]);
            unsigned q2 = umn(umx(s1[2], s1[3]), umn(s2[2], s2[3]));
            m1 = umn(p1, q1);
            m2 = umn(umx(p1, q1), umn(p2, q2));
            #pragma unroll
            for (int m = 16; m <= 32; m <<= 1) {
                unsigned o1 = __shfl_xor(m1, m, 64), o2 = __shfl_xor(m2, m, 64);
                unsigned nm2 = umn(umx(m1, o1), umn(m2, o2));
                m1 = umn(m1, o1); m2 = nm2;
            }
        }
        const float d1m = __uint_as_float(m1 & 0xFFFFFE00u);   // scaled x256
        const float d2m = __uint_as_float(m2 & 0xFFFFFE00u);
        const bool  amb = (d2m - d1m) <= 0.030720f;            // 256 * 1.2e-4

        int bj;
        if (__ballot(amb) == 0ULL) {
            bj = (int)(m1 & 511u);
            if (l < 16) {
                out[IDX_OFF + px] = (float)bj;
                float dd = __uint_as_float((m1 & 0xFFFFFE00u) | 0x100u);
                ls += __fmaf_rn(dd, 0.00390625f, apx - 0.5f);
            }
        } else {
            unsigned k1, k2, k3;
            {
                #define MERGE3(o1,o2,o3, a1,a2,a3, b1,b2,b3)                 \
                    o1 = umn(a1, b1);                                        \
                    o2 = med3u(a1, b1, umn(a2, b2));                         \
                    o3 = umn(umn(a3, b3), umn(umx(a2, b1), umx(a1, b2)));
                unsigned x1,x2,x3, y1,y2,y3;
                MERGE3(x1,x2,x3, s1[0],s2[0],s3[0], s1[1],s2[1],s3[1]);
                MERGE3(y1,y2,y3, s1[2],s2[2],s3[2], s1[3],s2[3],s3[3]);
                MERGE3(k1,k2,k3, x1,x2,x3, y1,y2,y3);
                #undef MERGE3
            }
            float zr[64];
            #pragma unroll
            for (int c = 0; c < 64; ++c) zr[c] = zb[(size_t)c * HW];
            float ap;
            {   // numpy-exact ||z||^2
                float r[8];
                #pragma unroll
                for (int i = 0; i < 8; ++i) r[i] = __fmul_rn(zr[i], zr[i]);
                #pragma unroll
                for (int k = 8; k < 64; k += 8) {
                    #pragma unroll
                    for (int i = 0; i < 8; ++i)
                        r[i] = __fadd_rn(r[i], __fmul_rn(zr[k+i], zr[k+i]));
                }
                ap = __fadd_rn(
                    __fadd_rn(__fadd_rn(r[0],r[1]), __fadd_rn(r[2],r[3])),
                    __fadd_rn(__fadd_rn(r[4],r[5]), __fadd_rn(r[6],r[7])));
            }
            const float thr = d1m + 0.030720f;
            float bd = 3.0e38f; bj = 1023;

            #define RESCORE(K) do {                                               \
                float da_ = __uint_as_float((K) & 0xFFFFFE00u);                   \
                if (da_ <= thr) {                                                 \
                    int j_ = (int)((K) & 511u);                                   \
                    const float* er_ = cb + (size_t)j_ * 64;                      \
                    float a_ = 0.f;                                               \
                    _Pragma("unroll")                                             \
                    for (int c_ = 0; c_ < 64; ++c_)                               \
                        a_ = __fmaf_rn(zr[c_], er_[c_], a_);                      \
                    float dd_ = __fsub_rn(__fadd_rn(ap, eshx[j_]),                \
                                          __fmul_rn(2.0f, a_));                   \
                    if (dd_ < bd || (dd_ == bd && j_ < bj)) { bd = dd_; bj = j_; }\
                }                                                                 \
            } while (0)
            RESCORE(k1); RESCORE(k2); RESCORE(k3);
            #undef RESCORE

            #pragma unroll
            for (int m = 16; m <= 32; m <<= 1) {   // lexicographic (d,j) merge
                float od = __shfl_xor(bd, m, 64);
                int   oj = __shfl_xor(bj, m, 64);
                if (od < bd || (od == bd && oj < bj)) { bd = od; bj = oj; }
            }
            if (l < 16) {
                out[IDX_OFF + px] = (float)bj;
                ls += bd;
            }
        }
        if (pt == 0) bjA = bj; else bjB = bj;
    }

    // ---- z_q write: both tiles together -> full 128B lines (r12 form) ----
    {
        const int pm  = l & 31;
        const int hh  = l >> 5;
        int b0 = __shfl(bjA, pm & 15, 64);
        int b1 = __shfl(bjB, pm & 15, 64);
        const int bjw = (pm >> 4) ? b1 : b0;
        const float* eb = cb + (size_t)bjw * 64;
        float* zq = out + ZQ_OFF + (size_t)bb * (C_DIM * HW) + ((pxw0 + pm) & (HW-1));
        #pragma unroll
        for (int cc = 0; cc < 32; ++cc) {
            int c = hh * 32 + cc;
            zq[(size_t)c * HW] = eb[c];    // 32 px x 2 planes = 2 full lines/instr
        }
    }

    // ---- loss reduce: wave -> block -> ws ----
    #pragma unroll
    for (int off = 32; off; off >>= 1) ls += __shfl_down(ls, off, 64);
    if (l == 0) wsum[wv] = ls;
    __syncthreads();
    if (t == 0) {
        float s = 0.f;
        #pragma unroll
        for (int i = 0; i < 8; ++i) s += wsum[i];
        ws[blockIdx.x] = s;
    }
}

__global__ __launch_bounds__(256) void vq_loss(
    const float* __restrict__ ws, float* __restrict__ out)
{
    __shared__ float sm[4];
    float v = ws[threadIdx.x] + ws[threadIdx.x + 256];   // 512 partials
    #pragma unroll
    for (int off = 32; off; off >>= 1) v += __shfl_down(v, off, 64);
    const int lane = threadIdx.x & 63, wid = threadIdx.x >> 6;
    if (lane == 0) sm[wid] = v;
    __syncthreads();
    if (threadIdx.x == 0)
        out[0] = ((sm[0] + sm[1]) + (sm[2] + sm[3])) * (1.0f / 8388608.0f);
}

extern "C" void kernel_launch(void* const* d_in, const int* in_sizes, int n_in,
                              void* d_out, int out_size, void* d_ws, size_t ws_size,
                              hipStream_t stream)
{
    const float* z  = (const float*)d_in[0];   // 8388608 f32
    const float* cb = (const float*)d_in[1];   // 32768 f32
    float* out = (float*)d_out;
    float* ws  = (float*)d_ws;                 // 512 f32 partials

    vq_main<<<NBLK, TPB, 0, stream>>>(z, cb, out, ws);
    vq_loss<<<1, 256, 0, stream>>>(ws, out);
}